// Round 1
// baseline (120.975 us; speedup 1.0000x reference)
//
#include <hip/hip_runtime.h>

#define IMG_H 1080
#define IMG_W 1920
#define CH 3
#define BATCH 4

#define BW 32
#define BH 8
#define PW (BW + 2)   // 34
#define PH (BH + 2)   // 10

__global__ __launch_bounds__(BW * BH)
void dssim_l1_kernel(const float* __restrict__ pred,
                     const float* __restrict__ gt,
                     float* __restrict__ out) {
    const float C1 = 0.01f * 0.01f;
    const float C2 = 0.03f * 0.03f;
    const float ALPHA = 0.85f;

    __shared__ float sx[PH][PW];
    __shared__ float sy[PH][PW];

    const int tx = threadIdx.x;              // 0..31
    const int ty = threadIdx.y;              // 0..7
    const int tid = ty * BW + tx;

    const int tile_w0 = blockIdx.x * BW;
    const int tile_h0 = blockIdx.y * BH;
    const int b = blockIdx.z;

    const int ow = tile_w0 + tx;
    const int oh = tile_h0 + ty;

    float ssim_sum = 0.0f;
    float l1_sum = 0.0f;

    for (int c = 0; c < CH; ++c) {
        const float* __restrict__ xin = pred + ((size_t)(b * CH + c)) * IMG_H * IMG_W;
        const float* __restrict__ yin = gt   + ((size_t)(b * CH + c)) * IMG_H * IMG_W;

        // Stage reflection-padded (PH x PW) tile of both inputs into LDS.
        for (int idx = tid; idx < PH * PW; idx += BW * BH) {
            int r   = idx / PW;
            int col = idx - r * PW;
            int gh = tile_h0 - 1 + r;
            int gw = tile_w0 - 1 + col;
            // reflect pad by 1: -1 -> 1, N -> N-2
            gh = (gh < 0) ? 1 : ((gh >= IMG_H) ? (2 * IMG_H - 2 - gh) : gh);
            gw = (gw < 0) ? 1 : ((gw >= IMG_W) ? (2 * IMG_W - 2 - gw) : gw);
            size_t gidx = (size_t)gh * IMG_W + gw;
            sx[r][col] = xin[gidx];
            sy[r][col] = yin[gidx];
        }
        __syncthreads();

        float ax = 0.f, ay = 0.f, axx = 0.f, ayy = 0.f, axy = 0.f;
#pragma unroll
        for (int dy = 0; dy < 3; ++dy) {
#pragma unroll
            for (int dx = 0; dx < 3; ++dx) {
                float xv = sx[ty + dy][tx + dx];
                float yv = sy[ty + dy][tx + dx];
                ax  += xv;
                ay  += yv;
                axx += xv * xv;
                ayy += yv * yv;
                axy += xv * yv;
            }
        }

        const float inv9 = 1.0f / 9.0f;
        float mux = ax * inv9;
        float muy = ay * inv9;
        float sigx  = axx * inv9 - mux * mux;
        float sigy  = ayy * inv9 - muy * muy;
        float sigxy = axy * inv9 - mux * muy;

        float n = (2.0f * mux * muy + C1) * (2.0f * sigxy + C2);
        float d = (mux * mux + muy * muy + C1) * (sigx + sigy + C2);
        float s = (1.0f - n / d) * 0.5f;
        s = fminf(fmaxf(s, 0.0f), 1.0f);
        ssim_sum += s;

        float xc = sx[ty + 1][tx + 1];
        float yc = sy[ty + 1][tx + 1];
        l1_sum += fabsf(xc - yc);

        __syncthreads();  // protect LDS before next channel's staging
    }

    const float inv3 = 1.0f / 3.0f;
    float result = ALPHA * (ssim_sum * inv3) + (1.0f - ALPHA) * (l1_sum * inv3);
    out[(size_t)b * IMG_H * IMG_W + (size_t)oh * IMG_W + ow] = result;
}

extern "C" void kernel_launch(void* const* d_in, const int* in_sizes, int n_in,
                              void* d_out, int out_size, void* d_ws, size_t ws_size,
                              hipStream_t stream) {
    const float* pred = (const float*)d_in[0];
    const float* gt   = (const float*)d_in[1];
    float* out = (float*)d_out;

    dim3 block(BW, BH, 1);
    dim3 grid(IMG_W / BW, IMG_H / BH, BATCH);  // 60 x 135 x 4
    dssim_l1_kernel<<<grid, block, 0, stream>>>(pred, gt, out);
}

// Round 2
// 79.951 us; speedup vs baseline: 1.5131x; 1.5131x over previous
//
#include <hip/hip_runtime.h>

#define IMG_H 1080
#define IMG_W 1920
#define CH 3
#define BATCH 4

#define TW 64            // tile width (= blockDim.x)
#define TH 24            // tile height (1080 = 45*24)
#define RPT 6            // rows per thread (blockDim.y = 4)
#define NQ 18            // float4 per padded row: [tile_w0-4, tile_w0+68) = 72 floats
#define PR (TH + 2)      // padded rows = 26
#define PWF (NQ * 4)     // padded row floats = 72

__global__ __launch_bounds__(256)
void dssim_l1_kernel(const float* __restrict__ pred,
                     const float* __restrict__ gt,
                     float* __restrict__ out) {
    const float C1 = 0.01f * 0.01f;
    const float C2 = 0.03f * 0.03f;
    const float ALPHA = 0.85f;
    const float inv9 = 1.0f / 9.0f;
    const float inv3 = 1.0f / 3.0f;

    __shared__ float sx[PR][PWF];
    __shared__ float sy[PR][PWF];

    const int tx = threadIdx.x;            // 0..63
    const int ty = threadIdx.y;            // 0..3
    const int tid = ty * TW + tx;

    const int tile_w0 = blockIdx.x * TW;
    const int tile_h0 = blockIdx.y * TH;
    const int b = blockIdx.z;

    const bool ledge = (tile_w0 == 0);
    const bool redge = (tile_w0 == IMG_W - TW);

    float ssim_acc[RPT];
    float l1_acc[RPT];
#pragma unroll
    for (int o = 0; o < RPT; ++o) { ssim_acc[o] = 0.f; l1_acc[o] = 0.f; }

    for (int c = 0; c < CH; ++c) {
        const float* __restrict__ xin = pred + ((size_t)(b * CH + c)) * IMG_H * IMG_W;
        const float* __restrict__ yin = gt   + ((size_t)(b * CH + c)) * IMG_H * IMG_W;

        // ---- stage: PR rows x NQ float4, aligned, clamped at W borders ----
        for (int idx = tid; idx < PR * NQ; idx += 256) {
            int r = idx / NQ;
            int q = idx - r * NQ;
            int gh = tile_h0 - 1 + r;
            gh = (gh < 0) ? 1 : ((gh >= IMG_H) ? (2 * IMG_H - 2 - gh) : gh);
            int gw = tile_w0 - 4 + q * 4;
            gw = max(0, min(gw, IMG_W - 4));   // stays 4-aligned
            size_t base = (size_t)gh * IMG_W + gw;
            float4 xv = *reinterpret_cast<const float4*>(xin + base);
            float4 yv = *reinterpret_cast<const float4*>(yin + base);
            *reinterpret_cast<float4*>(&sx[r][q * 4]) = xv;
            *reinterpret_cast<float4*>(&sy[r][q * 4]) = yv;
        }
        __syncthreads();

        // ---- fix reflected W-border columns (only 2 of 30 block columns) ----
        if (ledge || redge) {
            if (tid < PR) {
                if (ledge) {                 // global col -1 (idx 3) = col 1 (idx 5)
                    sx[tid][3] = sx[tid][5];
                    sy[tid][3] = sy[tid][5];
                }
                if (redge) {                 // global col 1920 (idx 68) = col 1918 (idx 66)
                    sx[tid][68] = sx[tid][66];
                    sy[tid][68] = sy[tid][66];
                }
            }
            __syncthreads();
        }

        // ---- horizontal 3-tap sums for the 8 window rows this thread needs ----
        const int r0 = ty * RPT;             // LDS row base (tile-rel row - 1 maps to LDS row)
        float hx[RPT + 2], hy[RPT + 2], hxx[RPT + 2], hyy[RPT + 2], hxy[RPT + 2];
        float cx[RPT + 2], cy[RPT + 2];
#pragma unroll
        for (int i = 0; i < RPT + 2; ++i) {
            const float x0 = sx[r0 + i][tx + 3];
            const float x1 = sx[r0 + i][tx + 4];
            const float x2 = sx[r0 + i][tx + 5];
            const float y0 = sy[r0 + i][tx + 3];
            const float y1 = sy[r0 + i][tx + 4];
            const float y2 = sy[r0 + i][tx + 5];
            hx[i]  = x0 + x1 + x2;
            hy[i]  = y0 + y1 + y2;
            hxx[i] = x0 * x0 + x1 * x1 + x2 * x2;
            hyy[i] = y0 * y0 + y1 * y1 + y2 * y2;
            hxy[i] = x0 * y0 + x1 * y1 + x2 * y2;
            cx[i] = x1; cy[i] = y1;
        }

        // ---- vertical sums + SSIM per output row ----
#pragma unroll
        for (int o = 0; o < RPT; ++o) {
            float ax  = hx[o]  + hx[o + 1]  + hx[o + 2];
            float ay  = hy[o]  + hy[o + 1]  + hy[o + 2];
            float axx = hxx[o] + hxx[o + 1] + hxx[o + 2];
            float ayy = hyy[o] + hyy[o + 1] + hyy[o + 2];
            float axy = hxy[o] + hxy[o + 1] + hxy[o + 2];

            float mux = ax * inv9;
            float muy = ay * inv9;
            float sigx  = axx * inv9 - mux * mux;
            float sigy  = ayy * inv9 - muy * muy;
            float sigxy = axy * inv9 - mux * muy;

            float n = (2.0f * mux * muy + C1) * (2.0f * sigxy + C2);
            float d = (mux * mux + muy * muy + C1) * (sigx + sigy + C2);
            float s = (1.0f - n / d) * 0.5f;
            s = fminf(fmaxf(s, 0.0f), 1.0f);
            ssim_acc[o] += s;
            l1_acc[o] += fabsf(cx[o + 1] - cy[o + 1]);
        }

        __syncthreads();   // protect LDS before next channel's staging
    }

    const int ow = tile_w0 + tx;
#pragma unroll
    for (int o = 0; o < RPT; ++o) {
        const int oh = tile_h0 + ty * RPT + o;
        float result = ALPHA * (ssim_acc[o] * inv3) + (1.0f - ALPHA) * (l1_acc[o] * inv3);
        out[((size_t)b * IMG_H + oh) * IMG_W + ow] = result;
    }
}

extern "C" void kernel_launch(void* const* d_in, const int* in_sizes, int n_in,
                              void* d_out, int out_size, void* d_ws, size_t ws_size,
                              hipStream_t stream) {
    const float* pred = (const float*)d_in[0];
    const float* gt   = (const float*)d_in[1];
    float* out = (float*)d_out;

    dim3 block(TW, 4, 1);
    dim3 grid(IMG_W / TW, IMG_H / TH, BATCH);   // 30 x 45 x 4
    dssim_l1_kernel<<<grid, block, 0, stream>>>(pred, gt, out);
}

// Round 3
// 73.972 us; speedup vs baseline: 1.6354x; 1.0808x over previous
//
#include <hip/hip_runtime.h>

#define IMG_H 1080
#define IMG_W 1920
#define CH 3
#define TH 27            // rows per thread strip; 1080 = 40 * 27

__global__ __launch_bounds__(256)
void dssim_l1_kernel(const float* __restrict__ pred,
                     const float* __restrict__ gt,
                     float* __restrict__ out) {
    constexpr float K1 = 81.0f * 0.0001f;        // 81*C1
    constexpr float K2 = 81.0f * 0.0009f;        // 81*C2
    constexpr float A3 = 0.85f / 3.0f;
    constexpr float B3 = 0.15f / 3.0f;

    const int tx    = threadIdx.x;                       // 0..63
    const int col   = blockIdx.x * 64 + tx;
    const int strip = blockIdx.y * 4 + threadIdx.y;      // 0..39
    const int h0    = strip * TH;
    const int b     = blockIdx.z;

    // reflect-clamped neighbor columns (branchless, computed once)
    const int cm1 = abs(col - 1);                        // col 0 -> 1
    const int cp1 = min(col + 1, 2 * (IMG_W - 1) - col - 1);  // col 1919 -> 1918

    const size_t img = (size_t)IMG_H * IMG_W;
    const float* xc[CH] = { pred + (size_t)b * CH * img,
                            pred + (size_t)b * CH * img + img,
                            pred + (size_t)b * CH * img + 2 * img };
    const float* yc[CH] = { gt + (size_t)b * CH * img,
                            gt + (size_t)b * CH * img + img,
                            gt + (size_t)b * CH * img + 2 * img };

    // rolling 3-row window sums per channel (all indices compile-time)
    float hx[CH][3], hy[CH][3], hxx[CH][3], hyy[CH][3], hxy[CH][3];
    float cxp[CH], cyp[CH];   // center value of the current window-center row

#define LOADROW(c, s, SAVE_CENTER)                                         \
    {                                                                      \
        float x0 = xc[c][off0], x1 = xc[c][off1], x2 = xc[c][off2];        \
        float y0 = yc[c][off0], y1 = yc[c][off1], y2 = yc[c][off2];        \
        hx[c][s]  = x0 + x1 + x2;                                          \
        hy[c][s]  = y0 + y1 + y2;                                          \
        hxx[c][s] = x0 * x0 + x1 * x1 + x2 * x2;                           \
        hyy[c][s] = y0 * y0 + y1 * y1 + y2 * y2;                           \
        hxy[c][s] = x0 * y0 + x1 * y1 + x2 * y2;                           \
        if (SAVE_CENTER) { cxp[c] = x1; cyp[c] = y1; }                     \
    }

    // ---- warmup: rows h0-1 (slot 0) and h0 (slot 1) ----
    {
        int gm = (h0 == 0) ? 1 : h0 - 1;                 // reflect(-1) = 1
        int off0 = gm * IMG_W + cm1;
        int off1 = gm * IMG_W + col;
        int off2 = gm * IMG_W + cp1;
#pragma unroll
        for (int c = 0; c < CH; ++c) LOADROW(c, 0, false);
        off0 = h0 * IMG_W + cm1;
        off1 = h0 * IMG_W + col;
        off2 = h0 * IMG_W + cp1;
#pragma unroll
        for (int c = 0; c < CH; ++c) LOADROW(c, 1, true);
    }

    float* op = out + ((size_t)b * IMG_H + h0) * IMG_W + col;

    // ---- main loop: 27 rows, unrolled by 3 for static slot rotation ----
    for (int kc = 0; kc < TH / 3; ++kc) {
#pragma unroll
        for (int kk = 0; kk < 3; ++kk) {
            const int k = kc * 3 + kk;
            const int r = h0 + k + 1;                    // row entering the window
            const int gr = min(r, 2 * (IMG_H - 1) - r);  // reflect 1080 -> 1078
            const int snew = (kk + 2) % 3;               // 2,0,1 rotation
            const int off0 = gr * IMG_W + cm1;
            const int off1 = gr * IMG_W + col;
            const int off2 = gr * IMG_W + cp1;

            float res = 0.0f;
#pragma unroll
            for (int c = 0; c < CH; ++c) {
                float l1 = fabsf(cxp[c] - cyp[c]);       // center row = h0+k
                LOADROW(c, snew, true);                  // loads row h0+k+1

                float ax  = hx[c][0]  + hx[c][1]  + hx[c][2];
                float ay  = hy[c][0]  + hy[c][1]  + hy[c][2];
                float axx = hxx[c][0] + hxx[c][1] + hxx[c][2];
                float ayy = hyy[c][0] + hyy[c][1] + hyy[c][2];
                float axy = hxy[c][0] + hxy[c][1] + hxy[c][2];

                // SSIM with mu/sigma scaled by 81 (the 81^2 cancels in n/d):
                // n = (2u+K1)(18*axy - 2u + K2), d = (v+K1)(9w - v + K2)
                float u = ax * ay;
                float v = fmaf(ay, ay, ax * ax);
                float w = axx + ayy;
                float num1 = fmaf(2.0f, u, K1);
                float num2 = fmaf(18.0f, axy, fmaf(-2.0f, u, K2));
                float den1 = v + K1;
                float den2 = fmaf(9.0f, w, K2) - v;
                float n = num1 * num2;
                float d = den1 * den2;
                float s = fmaf(-0.5f, n * __builtin_amdgcn_rcpf(d), 0.5f);
                s = fminf(fmaxf(s, 0.0f), 1.0f);
                res = fmaf(A3, s, fmaf(B3, l1, res));
            }
            *op = res;
            op += IMG_W;
        }
    }
#undef LOADROW
}

extern "C" void kernel_launch(void* const* d_in, const int* in_sizes, int n_in,
                              void* d_out, int out_size, void* d_ws, size_t ws_size,
                              hipStream_t stream) {
    const float* pred = (const float*)d_in[0];
    const float* gt   = (const float*)d_in[1];
    float* out = (float*)d_out;

    dim3 block(64, 4, 1);
    dim3 grid(IMG_W / 64, (IMG_H / TH) / 4, 4);   // 30 x 10 x 4
    dssim_l1_kernel<<<grid, block, 0, stream>>>(pred, gt, out);
}